// Round 1
// baseline (1059.736 us; speedup 1.0000x reference)
//
#include <hip/hip_runtime.h>
#include <stdint.h>

// ---------- types ----------
typedef __attribute__((ext_vector_type(8))) short  short8;   // 8 x bf16 (4 VGPRs)
typedef __attribute__((ext_vector_type(4))) float  f32x4;

#define K_DIM 4096
#define N_DIM 11008
#define M_DIM 8192
#define M_TILES 64   // 8192/128
#define N_TILES 86   // 11008/128

// RNE float -> bf16 bits
__device__ __forceinline__ unsigned short f2bf(float f) {
    union { float f; uint32_t u; } v; v.f = f;
    uint32_t u = v.u;
    return (unsigned short)((u + 0x7FFFu + ((u >> 16) & 1u)) >> 16);
}

// ---------- conversion kernels ----------
// x: fp32 -> bf16, 4 elems/thread
__global__ void cvt_x_kernel(const float* __restrict__ x,
                             unsigned short* __restrict__ xb, int n4) {
    int i = blockIdx.x * blockDim.x + threadIdx.x;
    if (i >= n4) return;
    float4 v = ((const float4*)x)[i];
    ushort4 o;
    o.x = f2bf(v.x); o.y = f2bf(v.y); o.z = f2bf(v.z); o.w = f2bf(v.w);
    ((ushort4*)xb)[i] = o;
}

// w: int32 (int8 values) -> bf16 (exact), 4 elems/thread
__global__ void cvt_w_kernel(const int* __restrict__ w,
                             unsigned short* __restrict__ wb, int n4) {
    int i = blockIdx.x * blockDim.x + threadIdx.x;
    if (i >= n4) return;
    int4 v = ((const int4*)w)[i];
    ushort4 o;
    o.x = f2bf((float)v.x); o.y = f2bf((float)v.y);
    o.z = f2bf((float)v.z); o.w = f2bf((float)v.w);
    ((ushort4*)wb)[i] = o;
}

// ---------- GEMM: y = xb @ wb^T * scale + bias ----------
// 128x128 tile, BK=32, 4 waves (2x2), each wave 64x64 via 4x4 frags of 16x16x32
#define GLOAD_LDS16(gsrc, ldst)                                                  \
    __builtin_amdgcn_global_load_lds(                                            \
        (const __attribute__((address_space(1))) void*)(gsrc),                   \
        (__attribute__((address_space(3))) void*)(ldst), 16, 0, 0)

__global__ __launch_bounds__(256) void gemm_kernel(
    const unsigned short* __restrict__ xb,   // [8192][4096] bf16
    const unsigned short* __restrict__ wb,   // [11008][4096] bf16
    const float* __restrict__ scale,         // [1]
    const float* __restrict__ bias,          // [11008]
    float* __restrict__ out)                 // [8192][11008]
{
    __shared__ unsigned short sA[128 * 32];  // 8 KiB
    __shared__ unsigned short sB[128 * 32];  // 8 KiB

    const int t    = threadIdx.x;
    const int lane = t & 63;
    const int wave = t >> 6;
    const int wm   = wave >> 1;      // 0..1
    const int wn   = wave & 1;       // 0..1

    const int bid = blockIdx.x;
    const int bn  = bid % N_TILES;
    const int bm  = bid / N_TILES;

    // --- staging addresses (linear LDS, matches global_load_lds lane layout) ---
    const int row_l = t >> 2;            // 0..63
    const int col8  = (t & 3) * 8;       // 0,8,16,24
    const unsigned short* srcA0 = xb + (size_t)(bm * 128 + row_l) * K_DIM + col8;
    const unsigned short* srcA1 = srcA0 + (size_t)64 * K_DIM;
    const unsigned short* srcB0 = wb + (size_t)(bn * 128 + row_l) * K_DIM + col8;
    const unsigned short* srcB1 = srcB0 + (size_t)64 * K_DIM;

    unsigned short* dA0 = &sA[t * 8];
    unsigned short* dA1 = &sA[2048 + t * 8];
    unsigned short* dB0 = &sB[t * 8];
    unsigned short* dB1 = &sB[2048 + t * 8];

    // --- fragment read addresses ---
    const int frow = lane & 15;          // M-row / N-col within 16
    const int fk   = (lane >> 4) * 8;    // K offset
    const unsigned short* rA = &sA[(wm * 64 + frow) * 32 + fk];
    const unsigned short* rB = &sB[(wn * 64 + frow) * 32 + fk];

    f32x4 acc[4][4];
    #pragma unroll
    for (int i = 0; i < 4; ++i)
        #pragma unroll
        for (int j = 0; j < 4; ++j)
            acc[i][j] = (f32x4){0.f, 0.f, 0.f, 0.f};

    for (int kt = 0; kt < K_DIM / 32; ++kt) {
        GLOAD_LDS16(srcA0, dA0);
        GLOAD_LDS16(srcA1, dA1);
        GLOAD_LDS16(srcB0, dB0);
        GLOAD_LDS16(srcB1, dB1);
        srcA0 += 32; srcA1 += 32; srcB0 += 32; srcB1 += 32;
        __syncthreads();   // drains vmcnt: staged tile visible

        short8 a[4], b[4];
        #pragma unroll
        for (int i = 0; i < 4; ++i) a[i] = *(const short8*)(rA + i * 16 * 32);
        #pragma unroll
        for (int j = 0; j < 4; ++j) b[j] = *(const short8*)(rB + j * 16 * 32);

        #pragma unroll
        for (int i = 0; i < 4; ++i)
            #pragma unroll
            for (int j = 0; j < 4; ++j)
                acc[i][j] = __builtin_amdgcn_mfma_f32_16x16x32_bf16(
                    a[i], b[j], acc[i][j], 0, 0, 0);

        __syncthreads();   // all waves done reading before next overwrite
    }

    // --- epilogue: y = acc*scale + bias ---
    const float s = scale[0];
    #pragma unroll
    for (int i = 0; i < 4; ++i) {
        const int row0 = bm * 128 + wm * 64 + i * 16 + (lane >> 4) * 4;
        #pragma unroll
        for (int j = 0; j < 4; ++j) {
            const int col = bn * 128 + wn * 64 + j * 16 + (lane & 15);
            const float bv = bias[col];
            float* o = out + (size_t)row0 * N_DIM + col;
            #pragma unroll
            for (int r = 0; r < 4; ++r)
                o[(size_t)r * N_DIM] = acc[i][j][r] * s + bv;
        }
    }
}

// ---------- launch ----------
extern "C" void kernel_launch(void* const* d_in, const int* in_sizes, int n_in,
                              void* d_out, int out_size, void* d_ws, size_t ws_size,
                              hipStream_t stream) {
    const float* x     = (const float*)d_in[0];
    const int*   w     = (const int*)d_in[1];
    const float* scale = (const float*)d_in[2];
    const float* bias  = (const float*)d_in[3];
    float*       out   = (float*)d_out;

    const size_t x_elems = (size_t)M_DIM * K_DIM;      // 33,554,432
    const size_t w_elems = (size_t)N_DIM * K_DIM;      // 45,088,768
    const size_t xb_bytes = x_elems * 2;               // 64 MiB
    const size_t wb_bytes = w_elems * 2;               // 86 MiB
    if (ws_size < xb_bytes + wb_bytes) return;         // scratch too small -> fail visibly

    unsigned short* xb = (unsigned short*)d_ws;
    unsigned short* wb = (unsigned short*)((char*)d_ws + xb_bytes);

    {
        int n4 = (int)(x_elems / 4);
        cvt_x_kernel<<<(n4 + 255) / 256, 256, 0, stream>>>(x, xb, n4);
    }
    {
        int n4 = (int)(w_elems / 4);
        cvt_w_kernel<<<(n4 + 255) / 256, 256, 0, stream>>>(w, wb, n4);
    }
    gemm_kernel<<<M_TILES * N_TILES, 256, 0, stream>>>(xb, wb, scale, bias, out);
}

// Round 2
// 749.146 us; speedup vs baseline: 1.4146x; 1.4146x over previous
//
#include <hip/hip_runtime.h>
#include <stdint.h>

// ---------- types ----------
typedef __attribute__((ext_vector_type(8))) short  short8;   // 8 x bf16
typedef __attribute__((ext_vector_type(4))) float  f32x4;

#define K_DIM 4096
#define N_DIM 11008
#define M_DIM 8192
#define BM 256
#define BN 256
#define BK 64
#define NT (K_DIM / BK)     // 64 K-tiles
#define MT2 (M_DIM / BM)    // 32
#define NT2 (N_DIM / BN)    // 43

// RNE float -> bf16 bits
__device__ __forceinline__ unsigned short f2bf(float f) {
    union { float f; uint32_t u; } v; v.f = f;
    uint32_t u = v.u;
    return (unsigned short)((u + 0x7FFFu + ((u >> 16) & 1u)) >> 16);
}

// ---------- conversion kernels ----------
__global__ void cvt_x_kernel(const float* __restrict__ x,
                             unsigned short* __restrict__ xb, int n4) {
    int i = blockIdx.x * blockDim.x + threadIdx.x;
    if (i >= n4) return;
    float4 v = ((const float4*)x)[i];
    ushort4 o;
    o.x = f2bf(v.x); o.y = f2bf(v.y); o.z = f2bf(v.z); o.w = f2bf(v.w);
    ((ushort4*)xb)[i] = o;
}

__global__ void cvt_w_kernel(const int* __restrict__ w,
                             unsigned short* __restrict__ wb, int n4) {
    int i = blockIdx.x * blockDim.x + threadIdx.x;
    if (i >= n4) return;
    int4 v = ((const int4*)w)[i];
    ushort4 o;
    o.x = f2bf((float)v.x); o.y = f2bf((float)v.y);
    o.z = f2bf((float)v.z); o.w = f2bf((float)v.w);
    ((ushort4*)wb)[i] = o;
}

// ---------- 256x256 8-phase GEMM ----------
#define GLDS16(gsrc, ldst)                                                       \
    __builtin_amdgcn_global_load_lds(                                            \
        (const __attribute__((address_space(1))) void*)(gsrc),                   \
        (__attribute__((address_space(3))) void*)(ldst), 16, 0, 0)

// LDS map (bytes, per buffer of 64 KiB; 2 buffers = 128 KiB):
//   A: [0, 32768)  as rho_A = qm*128 + wm*64 + im*16 + (lane&15), row = 128 B
//   B: [32768,65536) as rho_B = qn*128 + wn*32 + (fn&1)*16 + (lane&15)
// Swizzle: physical inrow = logical inrow ^ ((rho&7)<<4)   (both sides)
// Stage regions (16 KiB each, 2 x global_load_lds of 8 KiB per thread-set):
//   A_Q: rho in [Q*128, Q*128+128)  -> global m = c*128 + Q*64 + (T>>3)
//   B_Q: rho in [Q*128, Q*128+128)  -> global n = c*128 + ((T>>3)>>5)*64 + Q*32 + ((T>>3)&31)

__global__ __launch_bounds__(512, 2) void gemm2_kernel(
    const unsigned short* __restrict__ xb,   // [8192][4096] bf16
    const unsigned short* __restrict__ wb,   // [11008][4096] bf16
    const float* __restrict__ scale,
    const float* __restrict__ bias,
    float* __restrict__ out)
{
    __shared__ unsigned char sm[131072];
    char* smc = (char*)sm;

    const int T  = threadIdx.x;
    const int l  = T & 63;
    const int wv = T >> 6;
    const int wm = wv >> 2;      // 0..1
    const int wn = wv & 3;       // 0..3

    // XCD-aware swizzle (1376 % 8 == 0)
    const int swz = (blockIdx.x & 7) * (MT2 * NT2 / 8) + (blockIdx.x >> 3);
    const int bm = swz / NT2;
    const int bn = swz - bm * NT2;
    const size_t rowM0 = (size_t)bm * BM;
    const size_t rowN0 = (size_t)bn * BN;

    // ---- staging precompute ----
    const int rowT = T >> 3;                                        // 0..63
    const int colT = ((((T & 7) * 16) ^ ((rowT & 7) << 4)) >> 1);   // pre-swizzled src col (elems)
    const unsigned short* pAg = xb + (rowM0 + rowT) * (size_t)K_DIM + colT;
    const unsigned short* pBg = wb + (rowN0 + ((rowT >> 5) << 6) + (rowT & 31)) * (size_t)K_DIM + colT;

    auto stageA = [&](int buf, int Q, int kt) {
        #pragma unroll
        for (int c = 0; c < 2; ++c) {
            const unsigned short* src = pAg + (size_t)(c * 128 + Q * 64) * K_DIM + (size_t)kt * BK;
            char* dst = smc + buf * 65536 + Q * 16384 + c * 8192 + T * 16;
            GLDS16(src, dst);
        }
    };
    auto stageB = [&](int buf, int Q, int kt) {
        #pragma unroll
        for (int c = 0; c < 2; ++c) {
            const unsigned short* src = pBg + (size_t)(c * 128 + Q * 32) * K_DIM + (size_t)kt * BK;
            char* dst = smc + buf * 65536 + 32768 + Q * 16384 + c * 8192 + T * 16;
            GLDS16(src, dst);
        }
    };

    // ---- ds_read precompute ----
    const int sw     = (l & 7) << 4;
    const int inrow0 = (l >> 4) * 16;
    const int lowk0  = inrow0 ^ sw;            // kk=0
    const int lowk1  = (64 + inrow0) ^ sw;     // kk=1
    const int arow   = wm * 64 + (l & 15);     // + qm*128 + im*16
    const int brow   = wn * 32 + (l & 15);     // + qn*128 + (fn&1)*16

    f32x4 acc[8][4];
    #pragma unroll
    for (int i = 0; i < 8; ++i)
        #pragma unroll
        for (int j = 0; j < 4; ++j)
            acc[i][j] = (f32x4){0.f, 0.f, 0.f, 0.f};

    short8 Ah[4][2], Bh[4][2];

    // ---- prologue: stage tiles 0 -> buf0, 1 -> buf1 (16 loads/thread) ----
    stageA(0, 0, 0); stageB(0, 0, 0); stageB(0, 1, 0); stageA(0, 1, 0);
    stageA(1, 0, 1); stageB(1, 0, 1); stageB(1, 1, 1); stageA(1, 1, 1);
    asm volatile("s_waitcnt vmcnt(8)" ::: "memory");   // tile 0 resident
    __builtin_amdgcn_s_barrier();
    __builtin_amdgcn_sched_barrier(0);

    for (int kt = 0; kt < NT; ++kt) {
        const int cur = kt & 1;
        char* baseA = smc + cur * 65536;
        char* baseB = baseA + 32768;
        const bool pf = (kt + 2 < NT);

        // ===== phase 0: qm=0, qn=0 — read Ah(q0) + Bh[0..1]; no stage =====
        #pragma unroll
        for (int im = 0; im < 4; ++im) {
            Ah[im][0] = *(const short8*)(baseA + (arow + im * 16) * 128 + lowk0);
            Ah[im][1] = *(const short8*)(baseA + (arow + im * 16) * 128 + lowk1);
        }
        #pragma unroll
        for (int fn = 0; fn < 2; ++fn) {
            Bh[fn][0] = *(const short8*)(baseB + (brow + fn * 16) * 128 + lowk0);
            Bh[fn][1] = *(const short8*)(baseB + (brow + fn * 16) * 128 + lowk1);
        }
        __builtin_amdgcn_s_barrier();
        __builtin_amdgcn_sched_barrier(0);
        __builtin_amdgcn_s_setprio(1);
        #pragma unroll
        for (int im = 0; im < 4; ++im)
            #pragma unroll
            for (int jn = 0; jn < 2; ++jn)
                #pragma unroll
                for (int kk = 0; kk < 2; ++kk)
                    acc[im][jn] = __builtin_amdgcn_mfma_f32_16x16x32_bf16(
                        Ah[im][kk], Bh[jn][kk], acc[im][jn], 0, 0, 0);
        __builtin_amdgcn_s_setprio(0);
        __builtin_amdgcn_s_barrier();
        __builtin_amdgcn_sched_barrier(0);

        // ===== phase 1: qm=0, qn=1 — read Bh[2..3]; stage A_Q0 + B_Q0 (t+2) =====
        #pragma unroll
        for (int fn = 2; fn < 4; ++fn) {
            Bh[fn][0] = *(const short8*)(baseB + 16384 + (brow + (fn & 1) * 16) * 128 + lowk0);
            Bh[fn][1] = *(const short8*)(baseB + 16384 + (brow + (fn & 1) * 16) * 128 + lowk1);
        }
        if (pf) { stageA(cur, 0, kt + 2); stageB(cur, 0, kt + 2); }
        __builtin_amdgcn_s_barrier();
        __builtin_amdgcn_sched_barrier(0);
        __builtin_amdgcn_s_setprio(1);
        #pragma unroll
        for (int im = 0; im < 4; ++im)
            #pragma unroll
            for (int jn = 0; jn < 2; ++jn)
                #pragma unroll
                for (int kk = 0; kk < 2; ++kk)
                    acc[im][2 + jn] = __builtin_amdgcn_mfma_f32_16x16x32_bf16(
                        Ah[im][kk], Bh[2 + jn][kk], acc[im][2 + jn], 0, 0, 0);
        __builtin_amdgcn_s_setprio(0);
        __builtin_amdgcn_s_barrier();
        __builtin_amdgcn_sched_barrier(0);

        // ===== phase 2: qm=1, qn=0 — read Ah(q1); stage B_Q1 (t+2) =====
        #pragma unroll
        for (int im = 0; im < 4; ++im) {
            Ah[im][0] = *(const short8*)(baseA + 16384 + (arow + im * 16) * 128 + lowk0);
            Ah[im][1] = *(const short8*)(baseA + 16384 + (arow + im * 16) * 128 + lowk1);
        }
        if (pf) stageB(cur, 1, kt + 2);
        __builtin_amdgcn_s_barrier();
        __builtin_amdgcn_sched_barrier(0);
        __builtin_amdgcn_s_setprio(1);
        #pragma unroll
        for (int im = 0; im < 4; ++im)
            #pragma unroll
            for (int jn = 0; jn < 2; ++jn)
                #pragma unroll
                for (int kk = 0; kk < 2; ++kk)
                    acc[4 + im][jn] = __builtin_amdgcn_mfma_f32_16x16x32_bf16(
                        Ah[im][kk], Bh[jn][kk], acc[4 + im][jn], 0, 0, 0);
        __builtin_amdgcn_s_setprio(0);
        __builtin_amdgcn_s_barrier();
        __builtin_amdgcn_sched_barrier(0);

        // ===== phase 3: qm=1, qn=1 — no reads; stage A_Q1 (t+2) =====
        if (pf) stageA(cur, 1, kt + 2);
        __builtin_amdgcn_s_barrier();
        __builtin_amdgcn_sched_barrier(0);
        __builtin_amdgcn_s_setprio(1);
        #pragma unroll
        for (int im = 0; im < 4; ++im)
            #pragma unroll
            for (int jn = 0; jn < 2; ++jn)
                #pragma unroll
                for (int kk = 0; kk < 2; ++kk)
                    acc[4 + im][2 + jn] = __builtin_amdgcn_mfma_f32_16x16x32_bf16(
                        Ah[im][kk], Bh[2 + jn][kk], acc[4 + im][2 + jn], 0, 0, 0);
        __builtin_amdgcn_s_setprio(0);
        // tile boundary: counted vmcnt (never 0 in steady state)
        if (kt + 2 < NT) {
            asm volatile("s_waitcnt vmcnt(8)" ::: "memory");
        } else if (kt + 1 < NT) {
            asm volatile("s_waitcnt vmcnt(0)" ::: "memory");
        }
        __builtin_amdgcn_s_barrier();
        __builtin_amdgcn_sched_barrier(0);
    }

    // ---- epilogue: y = acc*scale + bias ----
    const float s = scale[0];
    #pragma unroll
    for (int fm = 0; fm < 8; ++fm) {
        const size_t row0 = rowM0 + wm * 128 + fm * 16 + (l >> 4) * 4;
        #pragma unroll
        for (int fn = 0; fn < 4; ++fn) {
            const int col = (int)rowN0 + wn * 64 + fn * 16 + (l & 15);
            const float bv = bias[col];
            float* o = out + row0 * N_DIM + col;
            #pragma unroll
            for (int r = 0; r < 4; ++r)
                o[(size_t)r * N_DIM] = acc[fm][fn][r] * s + bv;
        }
    }
}

// ---------- launch ----------
extern "C" void kernel_launch(void* const* d_in, const int* in_sizes, int n_in,
                              void* d_out, int out_size, void* d_ws, size_t ws_size,
                              hipStream_t stream) {
    const float* x     = (const float*)d_in[0];
    const int*   w     = (const int*)d_in[1];
    const float* scale = (const float*)d_in[2];
    const float* bias  = (const float*)d_in[3];
    float*       out   = (float*)d_out;

    const size_t x_elems  = (size_t)M_DIM * K_DIM;
    const size_t w_elems  = (size_t)N_DIM * K_DIM;
    const size_t xb_bytes = x_elems * 2;
    const size_t wb_bytes = w_elems * 2;
    if (ws_size < xb_bytes + wb_bytes) return;

    unsigned short* xb = (unsigned short*)d_ws;
    unsigned short* wb = (unsigned short*)((char*)d_ws + xb_bytes);

    {
        int n4 = (int)(x_elems / 4);
        cvt_x_kernel<<<(n4 + 255) / 256, 256, 0, stream>>>(x, xb, n4);
    }
    {
        int n4 = (int)(w_elems / 4);
        cvt_w_kernel<<<(n4 + 255) / 256, 256, 0, stream>>>(w, wb, n4);
    }
    gemm2_kernel<<<MT2 * NT2, 512, 0, stream>>>(xb, wb, scale, bias, out);
}

// Round 3
// 707.215 us; speedup vs baseline: 1.4985x; 1.0593x over previous
//
#include <hip/hip_runtime.h>
#include <stdint.h>

// ---------- types ----------
typedef __attribute__((ext_vector_type(8))) short          short8;   // 8 x bf16
typedef __attribute__((ext_vector_type(8))) unsigned short u16x8;
typedef __attribute__((ext_vector_type(4))) float          f32x4;

#define K_DIM 4096
#define N_DIM 11008
#define M_DIM 8192
#define BM 256
#define BN 256
#define BK 64
#define NT (K_DIM / BK)     // 64 K-tiles
#define MT2 (M_DIM / BM)    // 32
#define NT2 (N_DIM / BN)    // 43

// RNE float -> bf16 bits
__device__ __forceinline__ unsigned short f2bf(float f) {
    union { float f; uint32_t u; } v; v.f = f;
    uint32_t u = v.u;
    return (unsigned short)((u + 0x7FFFu + ((u >> 16) & 1u)) >> 16);
}

// ---------- conversion kernels (8 elems/thread) ----------
__global__ void cvt_x_kernel(const float* __restrict__ x,
                             u16x8* __restrict__ xb, int n8) {
    int i = blockIdx.x * blockDim.x + threadIdx.x;
    if (i >= n8) return;
    const float4* p = (const float4*)x + 2 * (size_t)i;
    float4 a = p[0], b = p[1];
    u16x8 o;
    o[0] = f2bf(a.x); o[1] = f2bf(a.y); o[2] = f2bf(a.z); o[3] = f2bf(a.w);
    o[4] = f2bf(b.x); o[5] = f2bf(b.y); o[6] = f2bf(b.z); o[7] = f2bf(b.w);
    xb[i] = o;
}

__global__ void cvt_w_kernel(const int* __restrict__ w,
                             u16x8* __restrict__ wb, int n8) {
    int i = blockIdx.x * blockDim.x + threadIdx.x;
    if (i >= n8) return;
    const int4* p = (const int4*)w + 2 * (size_t)i;
    int4 a = p[0], b = p[1];
    u16x8 o;
    o[0] = f2bf((float)a.x); o[1] = f2bf((float)a.y);
    o[2] = f2bf((float)a.z); o[3] = f2bf((float)a.w);
    o[4] = f2bf((float)b.x); o[5] = f2bf((float)b.y);
    o[6] = f2bf((float)b.z); o[7] = f2bf((float)b.w);
    wb[i] = o;
}

// ---------- 256x256 8-phase GEMM (m201 schedule) ----------
#define GLDS16(gsrc, ldst)                                                       \
    __builtin_amdgcn_global_load_lds(                                            \
        (const __attribute__((address_space(1))) void*)(gsrc),                   \
        (__attribute__((address_space(3))) void*)(ldst), 16, 0, 0)

#define BARSCHED() do { __builtin_amdgcn_s_barrier();                            \
                        __builtin_amdgcn_sched_barrier(0); } while (0)

__global__ __launch_bounds__(512, 2) void gemm2_kernel(
    const unsigned short* __restrict__ xb,   // [8192][4096] bf16
    const unsigned short* __restrict__ wb,   // [11008][4096] bf16
    const float* __restrict__ scale,
    const float* __restrict__ bias,
    float* __restrict__ out)
{
    __shared__ unsigned char sm[131072];
    char* smc = (char*)sm;

    const int T  = threadIdx.x;
    const int l  = T & 63;
    const int wv = T >> 6;
    const int wm = wv >> 2;      // 0..1
    const int wn = wv & 3;       // 0..3

    // XCD-aware, bn-major grid map: xcd owns bm in [4*xcd, 4*xcd+4),
    // all XCDs sweep the same bn column together -> B panel shared via L3,
    // per-XCD A slice (8 MB) L3-resident.
    const int orig = blockIdx.x;
    const int xcd  = orig & 7;
    const int p    = orig >> 3;          // 0..171
    const int bm   = xcd * 4 + (p & 3);  // 0..31
    const int bn   = p >> 2;             // 0..42
    const size_t rowM0 = (size_t)bm * BM;
    const size_t rowN0 = (size_t)bn * BN;

    // ---- staging precompute (pre-swizzled global source, linear LDS dest) ----
    const int rowT = T >> 3;                                        // 0..63
    const int colT = ((((T & 7) * 16) ^ ((rowT & 7) << 4)) >> 1);   // elems
    const unsigned short* pAg = xb + (rowM0 + rowT) * (size_t)K_DIM + colT;
    const unsigned short* pBg = wb + (rowN0 + ((rowT >> 5) << 6) + (rowT & 31)) * (size_t)K_DIM + colT;

    // one call = one half(quadrant) region = 2 x global_load_lds
    auto stageA = [&](char* base, int Q, int kt) {
        #pragma unroll
        for (int c = 0; c < 2; ++c) {
            const unsigned short* src = pAg + (size_t)(c * 128 + Q * 64) * K_DIM + (size_t)kt * BK;
            char* dst = base + Q * 16384 + c * 8192 + T * 16;
            GLDS16(src, dst);
        }
    };
    auto stageB = [&](char* base, int Q, int kt) {
        #pragma unroll
        for (int c = 0; c < 2; ++c) {
            const unsigned short* src = pBg + (size_t)(c * 128 + Q * 32) * K_DIM + (size_t)kt * BK;
            char* dst = base + 32768 + Q * 16384 + c * 8192 + T * 16;
            GLDS16(src, dst);
        }
    };

    // ---- ds_read precompute ----
    const int sw     = (l & 7) << 4;
    const int inrow0 = (l >> 4) * 16;
    const int lowk0  = inrow0 ^ sw;            // kk=0
    const int lowk1  = (64 + inrow0) ^ sw;     // kk=1
    const int arow   = wm * 64 + (l & 15);
    const int brow   = wn * 32 + (l & 15);

    f32x4 acc[8][4];
    #pragma unroll
    for (int i = 0; i < 8; ++i)
        #pragma unroll
        for (int j = 0; j < 4; ++j)
            acc[i][j] = (f32x4){0.f, 0.f, 0.f, 0.f};

    short8 Ah[4][2], Bh[4][2];

    char* const b0 = smc;            // buf0
    char* const b1 = smc + 65536;    // buf1

#define READ_A(base)                                                             \
    _Pragma("unroll")                                                            \
    for (int im = 0; im < 4; ++im) {                                             \
        Ah[im][0] = *(const short8*)((base) + (arow + im * 16) * 128 + lowk0);   \
        Ah[im][1] = *(const short8*)((base) + (arow + im * 16) * 128 + lowk1);   \
    }
#define READ_B(base, f0)                                                         \
    _Pragma("unroll")                                                            \
    for (int f = 0; f < 2; ++f) {                                                \
        Bh[(f0) + f][0] = *(const short8*)((base) + (brow + f * 16) * 128 + lowk0); \
        Bh[(f0) + f][1] = *(const short8*)((base) + (brow + f * 16) * 128 + lowk1); \
    }
#define MFMAQ(mi, ni)                                                            \
    __builtin_amdgcn_s_setprio(1);                                               \
    _Pragma("unroll")                                                            \
    for (int im = 0; im < 4; ++im)                                               \
        _Pragma("unroll")                                                        \
        for (int jn = 0; jn < 2; ++jn)                                           \
            _Pragma("unroll")                                                    \
            for (int kk = 0; kk < 2; ++kk)                                       \
                acc[(mi) + im][(ni) + jn] = __builtin_amdgcn_mfma_f32_16x16x32_bf16( \
                    Ah[im][kk], Bh[(ni) + jn][kk], acc[(mi) + im][(ni) + jn], 0, 0, 0); \
    __builtin_amdgcn_s_setprio(0);

    // ---- prologue: tile 0 fully + tile 1 minus A1 (14 loads) ----
    stageA(b0, 0, 0); stageB(b0, 0, 0); stageB(b0, 1, 0); stageA(b0, 1, 0);
    stageA(b1, 0, 1); stageB(b1, 0, 1); stageB(b1, 1, 1);
    asm volatile("s_waitcnt vmcnt(6)" ::: "memory");   // tile 0 resident
    BARSCHED();

    for (int kt2 = 0; kt2 < NT / 2; ++kt2) {
        const int  E  = kt2 * 2;          // tile E -> buf0, tile E+1 -> buf1
        const bool st = (E + 2 < NT);

        // ======== tile E (buf0) ========
        // p0: read A-q0 + B-q0; stage A1(E+1 -> buf1)
        READ_A(b0);
        READ_B(b0 + 32768, 0);
        stageA(b1, 1, E + 1);
        asm volatile("s_waitcnt lgkmcnt(8)" ::: "memory");
        BARSCHED();
        MFMAQ(0, 0);
        BARSCHED();

        // p1: read B-q1; stage A0(E+2 -> buf0)
        READ_B(b0 + 32768 + 16384, 2);
        if (st) stageA(b0, 0, E + 2);
        BARSCHED();
        MFMAQ(0, 2);
        BARSCHED();

        // p2: read A-q1; stage B0(E+2 -> buf0)
        READ_A(b0 + 16384);
        if (st) stageB(b0, 0, E + 2);
        BARSCHED();
        MFMAQ(4, 0);
        BARSCHED();

        // p3: stage B1(E+2 -> buf0); boundary vmcnt
        if (st) stageB(b0, 1, E + 2);
        BARSCHED();
        MFMAQ(4, 2);
        if (st) asm volatile("s_waitcnt vmcnt(6)" ::: "memory");
        else    asm volatile("s_waitcnt vmcnt(0)" ::: "memory");
        BARSCHED();

        // ======== tile E+1 (buf1) ========
        // p0: read A-q0 + B-q0; stage A1(E+2 -> buf0)
        READ_A(b1);
        READ_B(b1 + 32768, 0);
        if (st) stageA(b0, 1, E + 2);
        asm volatile("s_waitcnt lgkmcnt(8)" ::: "memory");
        BARSCHED();
        MFMAQ(0, 0);
        BARSCHED();

        // p1: read B-q1; stage A0(E+3 -> buf1)
        READ_B(b1 + 32768 + 16384, 2);
        if (st) stageA(b1, 0, E + 3);
        BARSCHED();
        MFMAQ(0, 2);
        BARSCHED();

        // p2: read A-q1; stage B0(E+3 -> buf1)
        READ_A(b1 + 16384);
        if (st) stageB(b1, 0, E + 3);
        BARSCHED();
        MFMAQ(4, 0);
        BARSCHED();

        // p3: stage B1(E+3 -> buf1); boundary vmcnt
        if (st) stageB(b1, 1, E + 3);
        BARSCHED();
        MFMAQ(4, 2);
        if (st) asm volatile("s_waitcnt vmcnt(6)" ::: "memory");
        else    asm volatile("s_waitcnt vmcnt(0)" ::: "memory");
        BARSCHED();
    }

    // ---- epilogue: y = acc*scale + bias ----
    const float s = scale[0];
    #pragma unroll
    for (int fm = 0; fm < 8; ++fm) {
        const size_t row0 = rowM0 + wm * 128 + fm * 16 + (l >> 4) * 4;
        #pragma unroll
        for (int fn = 0; fn < 4; ++fn) {
            const int col = (int)rowN0 + wn * 64 + fn * 16 + (l & 15);
            const float bv = bias[col];
            float* o = out + row0 * N_DIM + col;
            #pragma unroll
            for (int r = 0; r < 4; ++r)
                o[(size_t)r * N_DIM] = acc[fm][fn][r] * s + bv;
        }
    }
}

// ---------- launch ----------
extern "C" void kernel_launch(void* const* d_in, const int* in_sizes, int n_in,
                              void* d_out, int out_size, void* d_ws, size_t ws_size,
                              hipStream_t stream) {
    const float* x     = (const float*)d_in[0];
    const int*   w     = (const int*)d_in[1];
    const float* scale = (const float*)d_in[2];
    const float* bias  = (const float*)d_in[3];
    float*       out   = (float*)d_out;

    const size_t x_elems  = (size_t)M_DIM * K_DIM;
    const size_t w_elems  = (size_t)N_DIM * K_DIM;
    const size_t xb_bytes = x_elems * 2;
    const size_t wb_bytes = w_elems * 2;
    if (ws_size < xb_bytes + wb_bytes) return;

    unsigned short* xbp = (unsigned short*)d_ws;
    unsigned short* wbp = (unsigned short*)((char*)d_ws + xb_bytes);

    {
        int n8 = (int)(x_elems / 8);
        cvt_x_kernel<<<(n8 + 255) / 256, 256, 0, stream>>>(x, (u16x8*)xbp, n8);
    }
    {
        int n8 = (int)(w_elems / 8);
        cvt_w_kernel<<<(n8 + 255) / 256, 256, 0, stream>>>(w, (u16x8*)wbp, n8);
    }
    gemm2_kernel<<<MT2 * NT2, 512, 0, stream>>>(xbp, wbp, scale, bias, out);
}

// Round 5
// 677.875 us; speedup vs baseline: 1.5633x; 1.0433x over previous
//
#include <hip/hip_runtime.h>
#include <stdint.h>

// ---------- types ----------
typedef __attribute__((ext_vector_type(8))) short          short8;   // 8 x bf16
typedef __attribute__((ext_vector_type(8))) unsigned short u16x8;
typedef __attribute__((ext_vector_type(4))) float          f32x4;

#define K_DIM 4096
#define N_DIM 11008
#define M_DIM 8192
#define BM 256
#define BN 256
#define BK 64
#define NT (K_DIM / BK)     // 64 K-tiles
#define MT2 (M_DIM / BM)    // 32
#define NT2 (N_DIM / BN)    // 43

// RNE float -> bf16 bits
__device__ __forceinline__ unsigned short f2bf(float f) {
    union { float f; uint32_t u; } v; v.f = f;
    uint32_t u = v.u;
    return (unsigned short)((u + 0x7FFFu + ((u >> 16) & 1u)) >> 16);
}

// ---------- conversion kernels (8 elems/thread) ----------
__global__ void cvt_x_kernel(const float* __restrict__ x,
                             u16x8* __restrict__ xb, int n8) {
    int i = blockIdx.x * blockDim.x + threadIdx.x;
    if (i >= n8) return;
    const float4* p = (const float4*)x + 2 * (size_t)i;
    float4 a = p[0], b = p[1];
    u16x8 o;
    o[0] = f2bf(a.x); o[1] = f2bf(a.y); o[2] = f2bf(a.z); o[3] = f2bf(a.w);
    o[4] = f2bf(b.x); o[5] = f2bf(b.y); o[6] = f2bf(b.z); o[7] = f2bf(b.w);
    xb[i] = o;
}

__global__ void cvt_w_kernel(const int* __restrict__ w,
                             u16x8* __restrict__ wb, int n8) {
    int i = blockIdx.x * blockDim.x + threadIdx.x;
    if (i >= n8) return;
    const int4* p = (const int4*)w + 2 * (size_t)i;
    int4 a = p[0], b = p[1];
    u16x8 o;
    o[0] = f2bf((float)a.x); o[1] = f2bf((float)a.y);
    o[2] = f2bf((float)a.z); o[3] = f2bf((float)a.w);
    o[4] = f2bf((float)b.x); o[5] = f2bf((float)b.y);
    o[6] = f2bf((float)b.z); o[7] = f2bf((float)b.w);
    wb[i] = o;
}

// ---------- 256x256 GEMM, overlap schedule with gate->barrier->read ----------
#define GLDS16(gsrc, ldst)                                                       \
    __builtin_amdgcn_global_load_lds(                                            \
        (const __attribute__((address_space(1))) void*)(gsrc),                   \
        (__attribute__((address_space(3))) void*)(ldst), 16, 0, 0)

#define BARSCHED() do { __builtin_amdgcn_s_barrier();                            \
                        __builtin_amdgcn_sched_barrier(0); } while (0)

__global__ __launch_bounds__(512, 2) void gemm2_kernel(
    const unsigned short* __restrict__ xb,   // [8192][4096] bf16
    const unsigned short* __restrict__ wb,   // [11008][4096] bf16
    const float* __restrict__ scale,
    const float* __restrict__ bias,
    float* __restrict__ out)
{
    __shared__ unsigned char sm[131072];
    char* smc = (char*)sm;

    const int T  = threadIdx.x;
    const int l  = T & 63;
    const int wv = T >> 6;
    const int wm = wv >> 2;      // 0..1
    const int wn = wv & 3;       // 0..3

    // XCD-aware, bn-major grid map (B panel shared across XCDs via L3)
    const int orig = blockIdx.x;
    const int xcd  = orig & 7;
    const int p    = orig >> 3;          // 0..171
    const int bm   = xcd * 4 + (p & 3);  // 0..31
    const int bn   = p >> 2;             // 0..42
    const size_t rowM0 = (size_t)bm * BM;
    const size_t rowN0 = (size_t)bn * BN;

    // ---- staging precompute (pre-swizzled global source, linear LDS dest) ----
    const int rowT = T >> 3;                                        // 0..63
    const int colT = ((((T & 7) * 16) ^ ((rowT & 7) << 4)) >> 1);   // elems
    const unsigned short* pAg = xb + (rowM0 + rowT) * (size_t)K_DIM + colT;
    const unsigned short* pBg = wb + (rowN0 + ((rowT >> 5) << 6) + (rowT & 31)) * (size_t)K_DIM + colT;

    auto stageA = [&](char* base, int Q, int kt) {
        #pragma unroll
        for (int c = 0; c < 2; ++c) {
            const unsigned short* src = pAg + (size_t)(c * 128 + Q * 64) * K_DIM + (size_t)kt * BK;
            char* dst = base + Q * 16384 + c * 8192 + T * 16;
            GLDS16(src, dst);
        }
    };
    auto stageB = [&](char* base, int Q, int kt) {
        #pragma unroll
        for (int c = 0; c < 2; ++c) {
            const unsigned short* src = pBg + (size_t)(c * 128 + Q * 32) * K_DIM + (size_t)kt * BK;
            char* dst = base + 32768 + Q * 16384 + c * 8192 + T * 16;
            GLDS16(src, dst);
        }
    };

    // ---- ds_read precompute ----
    const int sw     = (l & 7) << 4;
    const int inrow0 = (l >> 4) * 16;
    const int lowk0  = inrow0 ^ sw;
    const int lowk1  = (64 + inrow0) ^ sw;
    const int arow   = wm * 64 + (l & 15);
    const int brow   = wn * 32 + (l & 15);

    f32x4 acc[8][4];
    #pragma unroll
    for (int i = 0; i < 8; ++i)
        #pragma unroll
        for (int j = 0; j < 4; ++j)
            acc[i][j] = (f32x4){0.f, 0.f, 0.f, 0.f};

    short8 Ah[4][2];   // current A quadrant (q0 then q1, then next tile's q0)
    short8 Bh[4][2];   // Bh[0..1]=B0(cur), Bh[2..3]=B1(cur)

    char* const b0 = smc;
    char* const b1 = smc + 65536;

#define READ_A(base)                                                             \
    _Pragma("unroll")                                                            \
    for (int im = 0; im < 4; ++im) {                                             \
        Ah[im][0] = *(const short8*)((base) + (arow + im * 16) * 128 + lowk0);   \
        Ah[im][1] = *(const short8*)((base) + (arow + im * 16) * 128 + lowk1);   \
    }
#define READ_B(base, f0)                                                         \
    _Pragma("unroll")                                                            \
    for (int f = 0; f < 2; ++f) {                                                \
        Bh[(f0) + f][0] = *(const short8*)((base) + (brow + f * 16) * 128 + lowk0); \
        Bh[(f0) + f][1] = *(const short8*)((base) + (brow + f * 16) * 128 + lowk1); \
    }
#define MFMAQ(mi, ni)                                                            \
    __builtin_amdgcn_s_setprio(1);                                               \
    _Pragma("unroll")                                                            \
    for (int im = 0; im < 4; ++im)                                               \
        _Pragma("unroll")                                                        \
        for (int jn = 0; jn < 2; ++jn)                                           \
            _Pragma("unroll")                                                    \
            for (int kk = 0; kk < 2; ++kk)                                       \
                acc[(mi) + im][(ni) + jn] = __builtin_amdgcn_mfma_f32_16x16x32_bf16( \
                    Ah[im][kk], Bh[(ni) + jn][kk], acc[(mi) + im][(ni) + jn], 0, 0, 0); \
    __builtin_amdgcn_s_setprio(0);

    // One tile:
    //  bcur = this tile's buffer, bnxt = next tile's buffer, EE = tile index
    //  ST0  = guard for p0's stage A1(EE+1)->bnxt
    //  STN  = guard for p1-p3 stages of tile EE+2 -> bcur
    //  RD   = guard for p3 cross-tile reads of tile EE+1 (from bnxt)
#define TILE_BODY(bcur, bnxt, EE, ST0, STN, RD)                                  \
    /* p0: read B1(cur) [resident since boundary]; stage A1(next) */             \
    READ_B((bcur) + 32768 + 16384, 2);                                           \
    if (ST0) stageA((bnxt), 1, (EE) + 1);                                        \
    BARSCHED();                                                                  \
    MFMAQ(0, 0);                    /* Aq0 x B0 */                               \
    __builtin_amdgcn_sched_barrier(0);                                           \
    /* p1: stage A0(EE+2); MFMA; then read Aq1(cur) [resident] */                \
    if (STN) stageA((bcur), 0, (EE) + 2);                                        \
    BARSCHED();                                                                  \
    MFMAQ(0, 2);                    /* Aq0 x B1 */                               \
    READ_A((bcur) + 16384);                                                      \
    __builtin_amdgcn_sched_barrier(0);                                           \
    /* p2: stage B0(EE+2); MFMA; vmcnt GATE for next tile's A0/B0 */             \
    if (STN) stageB((bcur), 0, (EE) + 2);                                        \
    BARSCHED();                                                                  \
    MFMAQ(4, 0);                    /* Aq1 x B0 */                               \
    if (STN) asm volatile("s_waitcnt vmcnt(8)" ::: "memory");                    \
    else     asm volatile("s_waitcnt vmcnt(4)" ::: "memory");                    \
    __builtin_amdgcn_sched_barrier(0);                                           \
    /* p3: stage B1(EE+2); BARRIER (completes gate->barrier->read);              \
           MFMA; cross-tile reads; boundary vmcnt; boundary barrier */           \
    if (STN) stageB((bcur), 1, (EE) + 2);                                        \
    BARSCHED();                                                                  \
    MFMAQ(4, 2);                    /* Aq1 x B1 */                               \
    if (RD) { READ_A(bnxt); READ_B((bnxt) + 32768, 0); }                         \
    if (STN) asm volatile("s_waitcnt vmcnt(6)" ::: "memory");                    \
    else     asm volatile("s_waitcnt vmcnt(0)" ::: "memory");                    \
    __builtin_amdgcn_s_barrier();   /* boundary: next tile resident */           \
    __builtin_amdgcn_sched_barrier(0);

    // ---- prologue ----
    // queue order must match steady-state entry: [A0(n+1),B0(n+1),B1(n+1)]
    stageA(b0, 0, 0); stageB(b0, 0, 0); stageB(b0, 1, 0); stageA(b0, 1, 0); // tile0: A0,B0,B1,A1
    stageA(b1, 0, 1); stageB(b1, 0, 1); stageB(b1, 1, 1);                   // tile1: A0,B0,B1
    asm volatile("s_waitcnt vmcnt(6)" ::: "memory");   // tile 0 resident
    __builtin_amdgcn_s_barrier();
    __builtin_amdgcn_sched_barrier(0);
    READ_A(b0);                 // Aq0(0)
    READ_B(b0 + 32768, 0);      // B0(0)
    __builtin_amdgcn_sched_barrier(0);

    for (int kt2 = 0; kt2 < NT / 2; ++kt2) {
        const int  E  = kt2 * 2;
        const bool st = (E + 2 < NT);
        // tile E in b0 (p0 stage A1(E+1) always valid: E+1 <= NT-1)
        TILE_BODY(b0, b1, E, true, st, true);
        // tile E+1 in b1 (p0 stage A1(E+2) guarded; p3 reads of tile E+2 guarded)
        TILE_BODY(b1, b0, E + 1, st, st, st);
    }

    // ---- epilogue: y = acc*scale + bias ----
    const float s = scale[0];
    #pragma unroll
    for (int fm = 0; fm < 8; ++fm) {
        const size_t row0 = rowM0 + wm * 128 + fm * 16 + (l >> 4) * 4;
        #pragma unroll
        for (int fn = 0; fn < 4; ++fn) {
            const int col = (int)rowN0 + wn * 64 + fn * 16 + (l & 15);
            const float bv = bias[col];
            float* o = out + row0 * N_DIM + col;
            #pragma unroll
            for (int r = 0; r < 4; ++r)
                o[(size_t)r * N_DIM] = acc[fm][fn][r] * s + bv;
        }
    }
}

// ---------- launch ----------
extern "C" void kernel_launch(void* const* d_in, const int* in_sizes, int n_in,
                              void* d_out, int out_size, void* d_ws, size_t ws_size,
                              hipStream_t stream) {
    const float* x     = (const float*)d_in[0];
    const int*   w     = (const int*)d_in[1];
    const float* scale = (const float*)d_in[2];
    const float* bias  = (const float*)d_in[3];
    float*       out   = (float*)d_out;

    const size_t x_elems  = (size_t)M_DIM * K_DIM;
    const size_t w_elems  = (size_t)N_DIM * K_DIM;
    const size_t xb_bytes = x_elems * 2;
    const size_t wb_bytes = w_elems * 2;
    if (ws_size < xb_bytes + wb_bytes) return;

    unsigned short* xbp = (unsigned short*)d_ws;
    unsigned short* wbp = (unsigned short*)((char*)d_ws + xb_bytes);

    {
        int n8 = (int)(x_elems / 8);
        cvt_x_kernel<<<(n8 + 255) / 256, 256, 0, stream>>>(x, (u16x8*)xbp, n8);
    }
    {
        int n8 = (int)(w_elems / 8);
        cvt_w_kernel<<<(n8 + 255) / 256, 256, 0, stream>>>(w, (u16x8*)wbp, n8);
    }
    gemm2_kernel<<<MT2 * NT2, 512, 0, stream>>>(xbp, wbp, scale, bias, out);
}